// Round 2
// baseline (31.806 us; speedup 1.0000x reference)
//
#include <hip/hip_runtime.h>

// Bspline control-grid -> dense flow field
// inputs: [B=16, T=25, 2*32*32] fp32  -> [N=400, 32, 32, 2] control grids
// output: [16, 25, 192, 192, 2] fp32 = -192 * bilinear_upsample(grid)
//
// Structure: 192 threads/block, block = 24 rows of one image (8 blocks/img).
// Each thread owns ONE x-pair (2 pixels, one float4 store) and loops over 12
// rows -> x-coordinate math hoisted out of the loop; control grid staged in
// LDS pre-scaled by -192.

#define GDIM 32
#define HOUT 192
#define WOUT 192
#define NIMG 400
#define ROWS_PER_BLOCK 24
#define BLOCKS_PER_IMG (HOUT / ROWS_PER_BLOCK)   // 8
#define THREADS 192
#define ROWS_PER_THREAD 12

typedef float f4 __attribute__((ext_vector_type(4)));

__global__ __launch_bounds__(THREADS) void bspline_flow_kernel(
    const float* __restrict__ in, float* __restrict__ out) {
  __shared__ float2 cgrid[GDIM * GDIM];  // 8 KB, pre-scaled by -192

  const int blk   = blockIdx.x;
  const int n     = blk >> 3;            // / BLOCKS_PER_IMG
  const int chunk = blk & 7;
  const int tid   = threadIdx.x;

  // Stage control grid into LDS, scaled by -192 (bilinear is linear in p).
  {
    const f4* src = reinterpret_cast<const f4*>(in + (size_t)n * (2 * GDIM * GDIM));
    f4* dst = reinterpret_cast<f4*>(cgrid);
    const float s = -192.0f;
    dst[tid]          = src[tid] * s;            // 0..191
    dst[tid + 192]    = src[tid + 192] * s;      // 192..383
    if (tid < 128)
      dst[tid + 384]  = src[tid + 384] * s;      // 384..511
  }
  __syncthreads();

  const int xp = tid % 96;               // x-pair index 0..95 (pixels 2xp, 2xp+1)
  const int g  = tid / 96;               // row half 0/1
  const int row0 = chunk * ROWS_PER_BLOCK + g * ROWS_PER_THREAD;

  const float qscale = 31.0f / 192.0f;

  // x-axis coords, hoisted (fixed per thread)
  const int   x    = 2 * xp;
  const float qx0  = (float)x * qscale;
  const float fx0  = floorf(qx0);
  const int   ix0  = (int)fx0;
  const float ax0  = qx0 - fx0, bx0 = 1.0f - ax0;
  const float qx1  = (float)(x + 1) * qscale;
  const float fx1  = floorf(qx1);
  const int   ix1  = (int)fx1;
  const float ax1  = qx1 - fx1, bx1 = 1.0f - ax1;

  f4* outv = reinterpret_cast<f4*>(out + (size_t)n * (HOUT * WOUT * 2));

#pragma unroll 2
  for (int i = 0; i < ROWS_PER_THREAD; ++i) {
    const int   y  = row0 + i;
    const float qy = (float)y * qscale;
    const float fy = floorf(qy);
    const int   y0 = (int)fy;
    const float ay = qy - fy, by = 1.0f - ay;

    const float2* rA = cgrid + y0 * GDIM;
    const float2* rB = rA + GDIM;

    const float2 p00 = rA[ix0];
    const float2 p01 = rA[ix0 + 1];
    const float2 p10 = rB[ix0];
    const float2 p11 = rB[ix0 + 1];
    const float2 q00 = rA[ix1];
    const float2 q01 = rA[ix1 + 1];
    const float2 q10 = rB[ix1];
    const float2 q11 = rB[ix1 + 1];

    // y-lerp then x-lerp (matches reference separable order)
    const float r0x = p00.x * by + p10.x * ay;
    const float r0y = p00.y * by + p10.y * ay;
    const float r1x = p01.x * by + p11.x * ay;
    const float r1y = p01.y * by + p11.y * ay;
    const float s0x = q00.x * by + q10.x * ay;
    const float s0y = q00.y * by + q10.y * ay;
    const float s1x = q01.x * by + q11.x * ay;
    const float s1y = q01.y * by + q11.y * ay;

    f4 o;
    o.x = r0x * bx0 + r1x * ax0;
    o.y = r0y * bx0 + r1y * ax0;
    o.z = s0x * bx1 + s1x * ax1;
    o.w = s0y * bx1 + s1y * ax1;

    __builtin_nontemporal_store(o, &outv[(size_t)y * 96 + xp]);
  }
}

extern "C" void kernel_launch(void* const* d_in, const int* in_sizes, int n_in,
                              void* d_out, int out_size, void* d_ws, size_t ws_size,
                              hipStream_t stream) {
  const float* in = (const float*)d_in[0];
  float* out = (float*)d_out;
  dim3 grid(NIMG * BLOCKS_PER_IMG);
  bspline_flow_kernel<<<grid, THREADS, 0, stream>>>(in, out);
}

// Round 3
// 27.272 us; speedup vs baseline: 1.1662x; 1.1662x over previous
//
#include <hip/hip_runtime.h>

// Bspline control-grid -> dense flow field
// inputs: [B=16, T=25, 2*32*32] fp32  -> [N=400, 32, 32, 2] control grids
// output: [16, 25, 192, 192, 2] fp32 = -192 * bilinear_upsample(grid)
//
// Separable structure (mirrors the reference): per block (16 output rows of
// one image), cooperatively compute the y-interpolated grid rows py[16][32][2]
// into LDS (pre-scaled by -192), then the hot loop is x-lerp only:
// 2 LDS float2 reads + 4 flops per pixel, 32 B stored per thread-iteration.

#define GDIM 32
#define HOUT 192
#define WOUT 192
#define NIMG 400
#define ROWS_PER_BLOCK 16
#define BLOCKS_PER_IMG (HOUT / ROWS_PER_BLOCK)   // 12
#define THREADS 256
#define QUADS_PER_ROW (WOUT / 4)                 // 48

typedef float f4 __attribute__((ext_vector_type(4)));

__global__ __launch_bounds__(THREADS) void bspline_flow_kernel(
    const float* __restrict__ in, float* __restrict__ out) {
  __shared__ float2 py[ROWS_PER_BLOCK][GDIM];   // y-lerped rows * -192 (4 KB)

  const int blk   = blockIdx.x;
  const int n     = blk / BLOCKS_PER_IMG;
  const int chunk = blk % BLOCKS_PER_IMG;
  const int tid   = threadIdx.x;
  const int row0  = chunk * ROWS_PER_BLOCK;

  const float qscale = 31.0f / 192.0f;

  // Stage: y-interpolate the control grid for this block's 16 rows.
  // 16 rows x 32 cols = 512 float2 -> 2 per thread. Reads hit L1/L2 (3.3 MB
  // total input); scale -192 folded into the lerp weights.
  {
    const float2* g = reinterpret_cast<const float2*>(in) + (size_t)n * (GDIM * GDIM);
#pragma unroll
    for (int s = 0; s < 2; ++s) {
      const int j  = tid + s * THREADS;      // 0..511
      const int r  = j >> 5;                 // local row 0..15
      const int c  = j & 31;                 // grid col 0..31
      const int y  = row0 + r;
      const float qy = (float)y * qscale;
      const float fy = floorf(qy);
      const int   y0 = (int)fy;              // <= 30 always
      const float ay = (qy - fy) * -192.0f;
      const float by = -192.0f - ay;         // (1-a) * -192
      const float2 gA = g[y0 * GDIM + c];
      const float2 gB = g[(y0 + 1) * GDIM + c];
      float2 v;
      v.x = gA.x * by + gB.x * ay;
      v.y = gA.y * by + gB.y * ay;
      py[r][c] = v;
    }
  }
  __syncthreads();

  f4* outv = reinterpret_cast<f4*>(out + (size_t)n * (HOUT * WOUT * 2));

  // Hot loop: 3 iterations, each = 4 pixels (one quad), 2 float4 stores.
#pragma unroll
  for (int it = 0; it < 3; ++it) {
    const int t  = tid + it * THREADS;       // 0..767
    const int yl = t / QUADS_PER_ROW;        // 0..15 (magic-mul)
    const int q  = t - yl * QUADS_PER_ROW;   // quad index 0..47
    const int y  = row0 + yl;
    const float2* prow = py[yl];

    float res[8];
#pragma unroll
    for (int k = 0; k < 4; ++k) {
      const int   x  = 4 * q + k;
      const float qx = (float)x * qscale;
      const float fx = floorf(qx);
      const int   x0 = (int)fx;              // <= 30 always
      const float ax = qx - fx, bx = 1.0f - ax;
      const float2 p0 = prow[x0];
      const float2 p1 = prow[x0 + 1];
      res[2 * k + 0] = p0.x * bx + p1.x * ax;
      res[2 * k + 1] = p0.y * bx + p1.y * ax;
    }

    f4 o0 = {res[0], res[1], res[2], res[3]};
    f4 o1 = {res[4], res[5], res[6], res[7]};
    const size_t base = (size_t)y * (WOUT / 2) + 2 * q;
    outv[base]     = o0;
    outv[base + 1] = o1;
  }
}

extern "C" void kernel_launch(void* const* d_in, const int* in_sizes, int n_in,
                              void* d_out, int out_size, void* d_ws, size_t ws_size,
                              hipStream_t stream) {
  const float* in = (const float*)d_in[0];
  float* out = (float*)d_out;
  dim3 grid(NIMG * BLOCKS_PER_IMG);
  bspline_flow_kernel<<<grid, THREADS, 0, stream>>>(in, out);
}